// Round 1
// baseline (613.399 us; speedup 1.0000x reference)
//
#include <hip/hip_runtime.h>
#include <math.h>

#define BB 32
#define TT 128
#define HH 256
#define MM 1000

// ---------------- ws layout (floats) ----------------
// e_cum   : 0         (4096)      cumsum of dur per (b,t)
// hcpre   : 4096      (32768)     conv output pre-LN (B,T,8)
// baseq   : 36864     (16384)     q-branch affine base (B,T,4)
// basep   : 53248     (8192)      p-branch affine base (B,T,2)
// h       : 61440     (1048576)   x@proj_w+proj_b (B,T,256)
// A       : 1110016   (4194304)   A[b][q*128+t][j]  (B,512,256)
// wc8     : 5304320   (256000)    per-(b,m) q*p combine (B,M,8)
// O1      : 5560320   (8192000)   intermediate (B,M,256)
// ml_i    : 13752320  (32 ints)

__global__ void k_prep(const float* __restrict__ dur, float* __restrict__ e_cum,
                       int* __restrict__ ml_i, float* __restrict__ ml_out) {
    int b = blockIdx.x;
    if (threadIdx.x == 0) {
        float run = 0.f;
        const float* d = dur + b * TT;
        float* e = e_cum + b * TT;
        for (int t = 0; t < TT; ++t) { run += d[t]; e[t] = run; }
        int ml = (int)rintf(run);          // round half-to-even, matches jnp.round
        if (ml > MM) ml = MM;
        if (ml < 0) ml = 0;
        ml_i[b] = ml;
        ml_out[b] = (float)ml;
    }
}

// h = x @ proj_w + proj_b   (B*T=4096 rows, 256x256)
// block: 256 thr, tile 16 rows x 256 cols; thread = 4 rows x 4 cols micro-tile
__global__ __launch_bounds__(256) void k_h(const float* __restrict__ x,
                                           const float* __restrict__ pw,
                                           const float* __restrict__ pb,
                                           float* __restrict__ h) {
    __shared__ float xs[16][HH];
    int blk = blockIdx.x;            // b*8 + tt
    int b = blk >> 3, tt = blk & 7;
    int t0 = tt * 16;
    int tid = threadIdx.x;
    for (int e = tid; e < 16 * HH; e += 256) {
        int r = e >> 8, i = e & 255;
        xs[r][i] = x[(b * TT + t0 + r) * HH + i];
    }
    __syncthreads();
    int jg = tid & 63, rg = tid >> 6;
    int j4 = jg * 4;
    float4 bias = *(const float4*)(pb + j4);
    float4 acc[4];
    #pragma unroll
    for (int ri = 0; ri < 4; ++ri) acc[ri] = bias;
    #pragma unroll 4
    for (int i = 0; i < HH; ++i) {
        float4 wv = *(const float4*)(pw + i * HH + j4);
        #pragma unroll
        for (int ri = 0; ri < 4; ++ri) {
            float xv = xs[rg * 4 + ri][i];
            acc[ri].x += wv.x * xv; acc[ri].y += wv.y * xv;
            acc[ri].z += wv.z * xv; acc[ri].w += wv.w * xv;
        }
    }
    #pragma unroll
    for (int ri = 0; ri < 4; ++ri)
        *(float4*)(h + (b * TT + t0 + rg * 4 + ri) * HH + j4) = acc[ri];
}

// conv 'SAME' K=3 over time, input h*valid; one block per (b, out-channel)
__global__ __launch_bounds__(128) void k_conv(const float* __restrict__ h,
                                              const float* __restrict__ cw,
                                              const int* __restrict__ xlen,
                                              float* __restrict__ hcpre) {
    int blk = blockIdx.x;            // b*8 + o
    int b = blk >> 3, o = blk & 7;
    int t = threadIdx.x;
    int L = xlen[b];
    float acc = 0.f;
    for (int k = 0; k < 3; ++k) {
        int tk = t + k - 1;
        if (tk < 0 || tk >= TT || tk >= L) continue;
        const float* hr = h + (b * TT + tk) * HH;
        const float* wr = cw + o * HH * 3 + k;
        float a = 0.f;
        for (int i = 0; i < HH; ++i) a += hr[i] * wr[i * 3];
        acc += a;
    }
    hcpre[(b * TT + t) * 8 + o] = acc;
}

// LN(8)+silu on conv out, then fold hc into per-(b,t) affine bases for both MLPs
__global__ __launch_bounds__(128) void k_bases(
    const float* __restrict__ hcpre, const float* __restrict__ cb,
    const float* __restrict__ cg, const float* __restrict__ cbeta,
    const float* __restrict__ qw1, const float* __restrict__ qb1,
    const float* __restrict__ pw1, const float* __restrict__ pb1,
    const float* __restrict__ e_cum, const float* __restrict__ dur,
    const int* __restrict__ xlen,
    float* __restrict__ baseq, float* __restrict__ basep) {
    int b = blockIdx.x;
    int t = threadIdx.x;
    int L = xlen[b];
    float v[8];
    float mu = 0.f;
    #pragma unroll
    for (int o = 0; o < 8; ++o) { v[o] = hcpre[(b * TT + t) * 8 + o] + cb[o]; mu += v[o]; }
    mu *= 0.125f;
    float var = 0.f;
    #pragma unroll
    for (int o = 0; o < 8; ++o) { float d = v[o] - mu; var += d * d; }
    var *= 0.125f;
    float rs = 1.0f / sqrtf(var + 1e-5f);
    float valid = (t < L) ? 1.f : 0.f;
    #pragma unroll
    for (int o = 0; o < 8; ++o) {
        float a = (v[o] - mu) * rs * cg[o] + cbeta[o];
        float s = a / (1.f + expf(-a));   // silu
        v[o] = s * valid;
    }
    float e = e_cum[b * TT + t];
    float s_ = e - dur[b * TT + t];
    #pragma unroll
    for (int j = 0; j < 4; ++j) {
        float acc = qb1[j];
        #pragma unroll
        for (int o = 0; o < 8; ++o) acc += v[o] * qw1[o * 4 + j];
        acc += e * qw1[9 * 4 + j] - s_ * qw1[8 * 4 + j];
        baseq[(b * TT + t) * 4 + j] = acc;
    }
    #pragma unroll
    for (int j = 0; j < 2; ++j) {
        float acc = pb1[j];
        #pragma unroll
        for (int o = 0; o < 8; ++o) acc += v[o] * pw1[o * 2 + j];
        acc += e * pw1[9 * 2 + j] - s_ * pw1[8 * 2 + j];
        basep[(b * TT + t) * 2 + j] = acc;
    }
}

// A[b][q*128+t][j] = sum_h x[b,t,h] * proj1_w[q*256+h, j]
__global__ __launch_bounds__(256) void k_A(const float* __restrict__ x,
                                           const float* __restrict__ p1w,
                                           float* __restrict__ A) {
    __shared__ float xs[16][HH];
    int blk = blockIdx.x;            // b*32 + q*8 + tt
    int b = blk >> 5;
    int rem = blk & 31;
    int q = rem >> 3, tt = rem & 7;
    int t0 = tt * 16;
    int tid = threadIdx.x;
    for (int e = tid; e < 16 * HH; e += 256) {
        int r = e >> 8, i = e & 255;
        xs[r][i] = x[(b * TT + t0 + r) * HH + i];
    }
    __syncthreads();
    int jg = tid & 63, rg = tid >> 6;
    int j4 = jg * 4;
    float4 acc[4];
    #pragma unroll
    for (int ri = 0; ri < 4; ++ri) { acc[ri].x = 0; acc[ri].y = 0; acc[ri].z = 0; acc[ri].w = 0; }
    #pragma unroll 4
    for (int i = 0; i < HH; ++i) {
        float4 wv = *(const float4*)(p1w + (q * HH + i) * HH + j4);
        #pragma unroll
        for (int ri = 0; ri < 4; ++ri) {
            float xv = xs[rg * 4 + ri][i];
            acc[ri].x += wv.x * xv; acc[ri].y += wv.y * xv;
            acc[ri].z += wv.z * xv; acc[ri].w += wv.w * xv;
        }
    }
    #pragma unroll
    for (int ri = 0; ri < 4; ++ri)
        *(float4*)(A + ((b * 4 + q) * TT + t0 + rg * 4 + ri) * HH + j4) = acc[ri];
}

// per (b,m): tiny MLPs (affine in m) -> softmax over t -> w, c, wc8, mel_mask
__global__ __launch_bounds__(128) void k_wsoft(
    const float* __restrict__ baseq, const float* __restrict__ basep,
    const float* __restrict__ qw1, const float* __restrict__ qg,
    const float* __restrict__ qbeta, const float* __restrict__ qw2,
    const float* __restrict__ qb2,
    const float* __restrict__ pw1, const float* __restrict__ pg,
    const float* __restrict__ pbeta, const float* __restrict__ pw2,
    const float* __restrict__ pb2,
    const int* __restrict__ xlen, const int* __restrict__ ml_i,
    float* __restrict__ w_out, float* __restrict__ mm_out,
    float* __restrict__ wc8) {
    int blk = blockIdx.x;
    int b = blk / MM;
    int m = blk - b * MM;
    int t = threadIdx.x;
    int ml = ml_i[b];
    bool pad = (m >= ml);
    mm_out[(b * MM + m) * TT + t] = pad ? 1.f : 0.f;
    if (pad) {
        #pragma unroll
        for (int q = 0; q < 4; ++q) w_out[((b * 4 + q) * MM + m) * TT + t] = 0.f;
        if (t < 8) wc8[(b * MM + m) * 8 + t] = 0.f;
        return;
    }
    int L = xlen[b];
    bool xm = (t >= L);
    float mp1 = (float)(m + 1);

    __shared__ float scs[4][TT];
    __shared__ float prod[8][TT];
    __shared__ float mx[4], sm[4];

    float sc[4];
    if (!xm) {
        float z[4];
        float4 bq = *(const float4*)(baseq + (b * TT + t) * 4);
        z[0] = bq.x; z[1] = bq.y; z[2] = bq.z; z[3] = bq.w;
        #pragma unroll
        for (int j = 0; j < 4; ++j)
            z[j] += mp1 * (qw1[8 * 4 + j] - qw1[9 * 4 + j]);
        float mu = 0.25f * (z[0] + z[1] + z[2] + z[3]);
        float var = 0.f;
        #pragma unroll
        for (int j = 0; j < 4; ++j) { float d = z[j] - mu; var += d * d; }
        var *= 0.25f;
        float rs = 1.f / sqrtf(var + 1e-5f);
        float a[4];
        #pragma unroll
        for (int j = 0; j < 4; ++j) {
            float av = (z[j] - mu) * rs * qg[j] + qbeta[j];
            a[j] = av / (1.f + expf(-av));
        }
        #pragma unroll
        for (int q = 0; q < 4; ++q) {
            float s = qb2[q];
            #pragma unroll
            for (int j = 0; j < 4; ++j) s += a[j] * qw2[j * 4 + q];
            sc[q] = s;
        }
    } else {
        #pragma unroll
        for (int q = 0; q < 4; ++q) sc[q] = -__builtin_inff();
    }
    #pragma unroll
    for (int q = 0; q < 4; ++q) scs[q][t] = sc[q];
    __syncthreads();
    if (t < 4) {
        float mxv = -__builtin_inff();
        for (int i = 0; i < TT; ++i) mxv = fmaxf(mxv, scs[t][i]);
        mx[t] = mxv;
    }
    __syncthreads();
    float wv[4];
    #pragma unroll
    for (int q = 0; q < 4; ++q) { wv[q] = expf(sc[q] - mx[q]); scs[q][t] = wv[q]; }
    __syncthreads();
    if (t < 4) {
        float s = 0.f;
        for (int i = 0; i < TT; ++i) s += scs[t][i];
        sm[t] = s;
    }
    __syncthreads();
    #pragma unroll
    for (int q = 0; q < 4; ++q) {
        wv[q] = wv[q] / sm[q];
        w_out[((b * 4 + q) * MM + m) * TT + t] = wv[q];
    }
    // c branch (p=2)
    float c0 = 0.f, c1 = 0.f;
    if (!xm) {
        float z0 = basep[(b * TT + t) * 2 + 0] + mp1 * (pw1[16 + 0] - pw1[18 + 0]);
        float z1 = basep[(b * TT + t) * 2 + 1] + mp1 * (pw1[16 + 1] - pw1[18 + 1]);
        float mu = 0.5f * (z0 + z1);
        float d0 = z0 - mu, d1 = z1 - mu;
        float var = 0.5f * (d0 * d0 + d1 * d1);
        float rs = 1.f / sqrtf(var + 1e-5f);
        float a0 = d0 * rs * pg[0] + pbeta[0];
        float a1 = d1 * rs * pg[1] + pbeta[1];
        a0 = a0 / (1.f + expf(-a0));
        a1 = a1 / (1.f + expf(-a1));
        c0 = pb2[0] + a0 * pw2[0] + a1 * pw2[2];
        c1 = pb2[1] + a0 * pw2[1] + a1 * pw2[3];
    }
    #pragma unroll
    for (int q = 0; q < 4; ++q) {
        prod[q * 2 + 0][t] = wv[q] * c0;
        prod[q * 2 + 1][t] = wv[q] * c1;
    }
    __syncthreads();
    if (t < 8) {
        float s = 0.f;
        for (int i = 0; i < TT; ++i) s += prod[t][i];
        wc8[(b * MM + m) * 8 + t] = s;
    }
}

// O1[b,m,j] = sum_{k=(q,t)} W[b,m,k]*A[b,k,j] + (p1b+p2b)[j] + wc8@proj2_w
__global__ __launch_bounds__(256) void k_gemm1(
    const float* __restrict__ w_out, const float* __restrict__ A,
    const float* __restrict__ wc8, const float* __restrict__ p1b,
    const float* __restrict__ p2b, const float* __restrict__ p2w,
    float* __restrict__ O1) {
    __shared__ float Wl[16][512];
    int blk = blockIdx.x;            // b*63 + mt
    int b = blk / 63;
    int mt = blk - b * 63;
    int m0 = mt * 16;
    int tid = threadIdx.x;
    for (int e = tid; e < 16 * 512; e += 256) {
        int mi = e >> 9;
        int k = e & 511;
        int q = k >> 7, t = k & 127;
        int m = m0 + mi;
        float v = 0.f;
        if (m < MM) v = w_out[((b * 4 + q) * MM + m) * TT + t];
        Wl[mi][k] = v;
    }
    __syncthreads();
    int jg = tid & 63, mg = tid >> 6;
    int j4 = jg * 4;
    const float4* A4 = (const float4*)(A + b * 512 * 256);
    float4 acc[4];
    #pragma unroll
    for (int mi = 0; mi < 4; ++mi) { acc[mi].x = 0; acc[mi].y = 0; acc[mi].z = 0; acc[mi].w = 0; }
    #pragma unroll 4
    for (int k = 0; k < 512; ++k) {
        float4 av = A4[k * 64 + jg];
        #pragma unroll
        for (int mi = 0; mi < 4; ++mi) {
            float wv = Wl[mg * 4 + mi][k];
            acc[mi].x += av.x * wv; acc[mi].y += av.y * wv;
            acc[mi].z += av.z * wv; acc[mi].w += av.w * wv;
        }
    }
    #pragma unroll
    for (int mi = 0; mi < 4; ++mi) {
        int m = m0 + mg * 4 + mi;
        if (m >= MM) continue;
        const float* c8 = wc8 + (b * MM + m) * 8;
        float4 o;
        o.x = p1b[j4 + 0] + p2b[j4 + 0];
        o.y = p1b[j4 + 1] + p2b[j4 + 1];
        o.z = p1b[j4 + 2] + p2b[j4 + 2];
        o.w = p1b[j4 + 3] + p2b[j4 + 3];
        #pragma unroll
        for (int qp = 0; qp < 8; ++qp) {
            float cv = c8[qp];
            o.x += cv * p2w[qp * 256 + j4 + 0];
            o.y += cv * p2w[qp * 256 + j4 + 1];
            o.z += cv * p2w[qp * 256 + j4 + 2];
            o.w += cv * p2w[qp * 256 + j4 + 3];
        }
        o.x += acc[mi].x; o.y += acc[mi].y; o.z += acc[mi].z; o.w += acc[mi].w;
        *(float4*)(O1 + (b * MM + m) * 256 + j4) = o;
    }
}

// O[b,m,kk] = (valid ? O1[b,m,:] @ projo_w[:,kk] + projo_b[kk] : projo_b[kk])
__global__ __launch_bounds__(256) void k_gemm2(
    const float* __restrict__ O1, const float* __restrict__ pow_,
    const float* __restrict__ pob, const int* __restrict__ ml_i,
    float* __restrict__ Oout) {
    __shared__ float Ol[16][256];
    int blk = blockIdx.x;            // b*126 + mt*2 + half
    int b = blk / 126;
    int rem = blk - b * 126;
    int mt = rem >> 1, half = rem & 1;
    int m0 = mt * 16;
    int tid = threadIdx.x;
    for (int e = tid; e < 16 * 256; e += 256) {
        int mi = e >> 8;
        int j = e & 255;
        int m = m0 + mi;
        Ol[mi][j] = (m < MM) ? O1[(b * MM + m) * 256 + j] : 0.f;
    }
    __syncthreads();
    int kg = tid & 63, mg = tid >> 6;
    int kk = half * 256 + kg * 4;
    float4 acc[4];
    #pragma unroll
    for (int mi = 0; mi < 4; ++mi) { acc[mi].x = 0; acc[mi].y = 0; acc[mi].z = 0; acc[mi].w = 0; }
    #pragma unroll 4
    for (int j = 0; j < 256; ++j) {
        float4 wv = *(const float4*)(pow_ + j * 512 + kk);
        #pragma unroll
        for (int mi = 0; mi < 4; ++mi) {
            float ov = Ol[mg * 4 + mi][j];
            acc[mi].x += wv.x * ov; acc[mi].y += wv.y * ov;
            acc[mi].z += wv.z * ov; acc[mi].w += wv.w * ov;
        }
    }
    int ml = ml_i[b];
    float4 bo = *(const float4*)(pob + kk);
    #pragma unroll
    for (int mi = 0; mi < 4; ++mi) {
        int m = m0 + mg * 4 + mi;
        if (m >= MM) continue;
        float4 o;
        if (m < ml) {
            o.x = acc[mi].x + bo.x; o.y = acc[mi].y + bo.y;
            o.z = acc[mi].z + bo.z; o.w = acc[mi].w + bo.w;
        } else {
            o = bo;
        }
        *(float4*)(Oout + (b * MM + m) * 512 + kk) = o;
    }
}

extern "C" void kernel_launch(void* const* d_in, const int* in_sizes, int n_in,
                              void* d_out, int out_size, void* d_ws, size_t ws_size,
                              hipStream_t stream) {
    (void)in_sizes; (void)n_in; (void)out_size; (void)ws_size;
    const float* x      = (const float*)d_in[0];
    // d_in[1] = x_mask (bool) — derived from x_lengths instead
    const float* dur    = (const float*)d_in[2];
    const int*   xlen   = (const int*)d_in[3];
    const float* proj_w = (const float*)d_in[4];
    const float* proj_b = (const float*)d_in[5];
    const float* conv_w = (const float*)d_in[6];
    const float* conv_b = (const float*)d_in[7];
    const float* conv_g = (const float*)d_in[8];
    const float* conv_be= (const float*)d_in[9];
    const float* q_w1   = (const float*)d_in[10];
    const float* q_b1   = (const float*)d_in[11];
    const float* q_g    = (const float*)d_in[12];
    const float* q_be   = (const float*)d_in[13];
    const float* q_w2   = (const float*)d_in[14];
    const float* q_b2   = (const float*)d_in[15];
    const float* p_w1   = (const float*)d_in[16];
    const float* p_b1   = (const float*)d_in[17];
    const float* p_g    = (const float*)d_in[18];
    const float* p_be   = (const float*)d_in[19];
    const float* p_w2   = (const float*)d_in[20];
    const float* p_b2   = (const float*)d_in[21];
    const float* p1w    = (const float*)d_in[22];
    const float* p1b    = (const float*)d_in[23];
    const float* p2w    = (const float*)d_in[24];
    const float* p2b    = (const float*)d_in[25];
    const float* pow_   = (const float*)d_in[26];
    const float* pob    = (const float*)d_in[27];

    float* ws    = (float*)d_ws;
    float* e_cum = ws + 0;
    float* hcpre = ws + 4096;
    float* baseq = ws + 36864;
    float* basep = ws + 53248;
    float* h     = ws + 61440;
    float* A     = ws + 1110016;
    float* wc8   = ws + 5304320;
    float* O1    = ws + 5560320;
    int*   ml_i  = (int*)(ws + 13752320);

    float* o_out  = (float*)d_out;                  // (B,M,512)
    float* mm_out = o_out + 16384000;               // (B,M,T)
    float* ml_out = o_out + 20480000;               // (B,)
    float* w_out  = o_out + 20480032;               // (B,Q,M,T)

    k_prep<<<dim3(BB), dim3(64), 0, stream>>>(dur, e_cum, ml_i, ml_out);
    k_h<<<dim3(BB * 8), dim3(256), 0, stream>>>(x, proj_w, proj_b, h);
    k_conv<<<dim3(BB * 8), dim3(128), 0, stream>>>(h, conv_w, xlen, hcpre);
    k_bases<<<dim3(BB), dim3(128), 0, stream>>>(hcpre, conv_b, conv_g, conv_be,
                                                q_w1, q_b1, p_w1, p_b1,
                                                e_cum, dur, xlen, baseq, basep);
    k_A<<<dim3(BB * 32), dim3(256), 0, stream>>>(x, p1w, A);
    k_wsoft<<<dim3(BB * MM), dim3(128), 0, stream>>>(baseq, basep,
                                                     q_w1, q_g, q_be, q_w2, q_b2,
                                                     p_w1, p_g, p_be, p_w2, p_b2,
                                                     xlen, ml_i, w_out, mm_out, wc8);
    k_gemm1<<<dim3(BB * 63), dim3(256), 0, stream>>>(w_out, A, wc8, p1b, p2b, p2w, O1);
    k_gemm2<<<dim3(BB * 126), dim3(256), 0, stream>>>(O1, pow_, pob, ml_i, o_out);
}